// Round 2
// baseline (512.443 us; speedup 1.0000x reference)
//
#include <hip/hip_runtime.h>

#define SEQ 1024
#define NT 256   // 4 waves; wave w owns units [32w, 32w+32) as 2 MFMA col-tiles

typedef _Float16 half8 __attribute__((ext_vector_type(8)));  // 4 VGPRs
typedef float f32x4 __attribute__((ext_vector_type(4)));     // MFMA 16x16 accum

// h buffer layout (halfwords): [buf][0..127]=h_hi, [buf][160..287]=h_lo.
// lo offset 160 hw = 80 words = bank shift 16 -> a wave's 8 distinct A-read
// addresses (hl in {0,1} x quad in {0..3}) cover all 32 banks exactly once.
#define LO_OFF 160
#define HBUF 320

__device__ __forceinline__ float sigmoidf_(float x) {
  float e = __expf(-x);
  return __builtin_amdgcn_rcpf(1.f + e);
}
__device__ __forceinline__ float tanhf_(float x) {
  float e = __expf(-2.f * x);
  return (1.f - e) * __builtin_amdgcn_rcpf(1.f + e);
}

__global__ __launch_bounds__(NT, 1)
void gru_kernel(const float* __restrict__ x,     // [B, S, 1]
                const float* __restrict__ w_ih,  // [3H, 1]
                const float* __restrict__ w_hh,  // [3H, H]
                const float* __restrict__ b_ih,  // [3H]
                const float* __restrict__ b_hh,  // [3H]
                const float* __restrict__ w_fc,  // [1, H]
                const float* __restrict__ b_fc,  // [1]
                float* __restrict__ out)         // [B, 1]
{
  __shared__ float xs[SEQ + 8];
  __shared__ __align__(16) _Float16 hs[2][HBUF];
  __shared__ float red[4];

  const int t = threadIdx.x;
  const int b = blockIdx.x;
  const int w = t >> 6;          // wave 0..3
  const int L = t & 63;          // lane
  const int n = L & 15;          // MFMA col (unit within tile) == A-row m
  const int quad = L >> 4;       // k-slice / C-row group
  const int hl = n & 1;          // A-row parity: even rows = h_hi, odd = h_lo
  const int u0 = 32 * w + n;     // col-tile 0 unit
  const int u1 = u0 + 16;        // col-tile 1 unit

  // stage x[b,:] (coalesced), zero-pad tail for the prefetch reads
  const float* xrow = x + (size_t)b * SEQ;
  for (int i = t; i < SEQ + 8; i += NT) xs[i] = (i < SEQ) ? xrow[i] : 0.f;
  for (int i = t; i < HBUF; i += NT) hs[0][i] = (_Float16)0.f;

  // B fragments (persistent, fp16): B[k=quad*8+i][col=n] = w_hh[(g*128+u)*128+k]
  half8 Bw[3][2][4];
#pragma unroll
  for (int g = 0; g < 3; ++g) {
#pragma unroll
    for (int c = 0; c < 2; ++c) {
      const float* row = w_hh + (size_t)(g * 128 + u0 + 16 * c) * 128;
#pragma unroll
      for (int kt = 0; kt < 4; ++kt) {
        union { _Float16 s[8]; half8 v; } tmp;
#pragma unroll
        for (int i = 0; i < 8; ++i) tmp.s[i] = (_Float16)row[kt * 32 + quad * 8 + i];
        Bw[g][c][kt] = tmp.v;
      }
    }
  }
  // per-unit scalars (n-dependent -> VGPRs), for both owned units
  const float bcr0 = b_ih[u0] + b_hh[u0];
  const float bcz0 = b_ih[128 + u0] + b_hh[128 + u0];
  const float bin0 = b_ih[256 + u0], bhn0 = b_hh[256 + u0];
  const float wir0 = w_ih[u0], wiz0 = w_ih[128 + u0], win0 = w_ih[256 + u0];
  const float bcr1 = b_ih[u1] + b_hh[u1];
  const float bcz1 = b_ih[128 + u1] + b_hh[128 + u1];
  const float bin1 = b_ih[256 + u1], bhn1 = b_hh[256 + u1];
  const float wir1 = w_ih[u1], wiz1 = w_ih[128 + u1], win1 = w_ih[256 + u1];

  // per-lane A-read base (halfwords): parity-selected hi/lo bank group
  const int abase = hl * LO_OFF + quad * 8;

  float h0 = 0.f, h1 = 0.f;  // h[u0], h[u1], replicated across quads
  __syncthreads();

#define MF(A, B, C) C = __builtin_amdgcn_mfma_f32_16x16x32_f16(A, B, C, 0, 0, 0)

  // One step: read buf RD, write buf WR. A even rows = h_hi, odd rows = h_lo.
  // C reg0 = even row (hi-dot), reg1 = odd row (lo-dot) for every quad:
  // d = C[0] + C[1] in-lane. Input-side preact folded into accumulator init
  // (reg0 only) so the post-MFMA chain is just one add per gate.
#define STEP(RD, WR, XT)                                                       \
  {                                                                            \
    const float xt = (XT);                                                     \
    half8 A[4];                                                                \
    _Pragma("unroll")                                                          \
    for (int kt = 0; kt < 4; ++kt)                                             \
      A[kt] = *(const half8*)&hs[RD][abase + kt * 32];                         \
    f32x4 ar0 = {fmaf(xt, wir0, bcr0), 0.f, 0.f, 0.f};                         \
    f32x4 az0 = {fmaf(xt, wiz0, bcz0), 0.f, 0.f, 0.f};                         \
    f32x4 an0 = {bhn0, 0.f, 0.f, 0.f};                                         \
    f32x4 ar1 = {fmaf(xt, wir1, bcr1), 0.f, 0.f, 0.f};                         \
    f32x4 az1 = {fmaf(xt, wiz1, bcz1), 0.f, 0.f, 0.f};                         \
    f32x4 an1 = {bhn1, 0.f, 0.f, 0.f};                                         \
    _Pragma("unroll")                                                          \
    for (int kt = 0; kt < 4; ++kt) {                                           \
      MF(A[kt], Bw[0][0][kt], ar0);                                            \
      MF(A[kt], Bw[1][0][kt], az0);                                            \
      MF(A[kt], Bw[2][0][kt], an0);                                            \
      MF(A[kt], Bw[0][1][kt], ar1);                                            \
      MF(A[kt], Bw[1][1][kt], az1);                                            \
      MF(A[kt], Bw[2][1][kt], an1);                                            \
    }                                                                          \
    const float r0 = sigmoidf_(ar0[0] + ar0[1]);                               \
    const float z0 = sigmoidf_(az0[0] + az0[1]);                               \
    const float nn0 =                                                          \
        tanhf_(fmaf(r0, an0[0] + an0[1], fmaf(xt, win0, bin0)));               \
    h0 = nn0 + z0 * (h0 - nn0);                                                \
    const float r1 = sigmoidf_(ar1[0] + ar1[1]);                               \
    const float z1 = sigmoidf_(az1[0] + az1[1]);                               \
    const float nn1 =                                                          \
        tanhf_(fmaf(r1, an1[0] + an1[1], fmaf(xt, win1, bin1)));               \
    h1 = nn1 + z1 * (h1 - nn1);                                                \
    if (quad < 2) {                                                            \
      const float hw = quad ? h1 : h0;                                        \
      const int uu = u0 + 16 * quad;                                           \
      const _Float16 hih = (_Float16)hw;                                       \
      hs[WR][uu] = hih;                                                        \
      hs[WR][LO_OFF + uu] = (_Float16)(hw - (float)hih);                       \
    }                                                                          \
    __syncthreads();                                                           \
  }

  float x0 = xs[0], x1 = xs[1];
  for (int s = 0; s < SEQ; s += 2) {
    const float x2 = xs[s + 2], x3 = xs[s + 3];  // prefetch next iter
    STEP(0, 1, x0);
    STEP(1, 0, x1);
    x0 = x2;
    x1 = x3;
  }
#undef STEP
#undef MF

  // epilogue: out[b] = relu(h_T) . w_fc + b_fc
  float v = 0.f;
  if (quad == 0) v = fmaxf(h0, 0.f) * w_fc[u0] + fmaxf(h1, 0.f) * w_fc[u1];
#pragma unroll
  for (int off = 1; off < 64; off <<= 1) v += __shfl_xor(v, off);
  if (L == 0) red[w] = v;
  __syncthreads();
  if (t == 0) out[b] = red[0] + red[1] + red[2] + red[3] + b_fc[0];
}

extern "C" void kernel_launch(void* const* d_in, const int* in_sizes, int n_in,
                              void* d_out, int out_size, void* d_ws, size_t ws_size,
                              hipStream_t stream) {
  const float* x    = (const float*)d_in[0];
  const float* w_ih = (const float*)d_in[1];
  const float* w_hh = (const float*)d_in[2];
  const float* b_ih = (const float*)d_in[3];
  const float* b_hh = (const float*)d_in[4];
  const float* w_fc = (const float*)d_in[5];
  const float* b_fc = (const float*)d_in[6];
  gru_kernel<<<256, NT, 0, stream>>>(x, w_ih, w_hh, b_ih, b_hh, w_fc, b_fc,
                                     (float*)d_out);
}

// Round 3
// 466.635 us; speedup vs baseline: 1.0982x; 1.0982x over previous
//
#include <hip/hip_runtime.h>

#define SEQ 1024
#define NT 512   // 8 waves; wave w owns gate-preact cols [16w,16w+16) for r,z,n

typedef _Float16 half8 __attribute__((ext_vector_type(8)));  // 4 VGPRs
typedef float f32x4 __attribute__((ext_vector_type(4)));     // MFMA 16x16 accum

// h buffer layout (halfwords): [buf][0..127]=h_hi, [buf][160..287]=h_lo.
// lo offset 160 hw = 80 words = bank shift 16 -> a wave's 8 distinct A-read
// addresses (hl in {0,1} x quad in {0..3}) cover all 32 banks exactly once.
#define LO_OFF 160
#define HBUF 320

__device__ __forceinline__ float sigmoidf_(float x) {
  float e = __expf(-x);
  return __builtin_amdgcn_rcpf(1.f + e);
}
__device__ __forceinline__ float tanhf_(float x) {
  float e = __expf(-2.f * x);
  return (1.f - e) * __builtin_amdgcn_rcpf(1.f + e);
}

__global__ __launch_bounds__(NT, 2)
void gru_kernel(const float* __restrict__ x,     // [B, S, 1]
                const float* __restrict__ w_ih,  // [3H, 1]
                const float* __restrict__ w_hh,  // [3H, H]
                const float* __restrict__ b_ih,  // [3H]
                const float* __restrict__ b_hh,  // [3H]
                const float* __restrict__ w_fc,  // [1, H]
                const float* __restrict__ b_fc,  // [1]
                float* __restrict__ out)         // [B, 1]
{
  __shared__ __align__(16) _Float16 hs[2][HBUF];
  __shared__ float red[8];

  const int t = threadIdx.x;
  const int b = blockIdx.x;
  const int w = t >> 6;          // wave 0..7
  const int L = t & 63;          // lane
  const int n = L & 15;          // MFMA col (unit in tile) == A-row m
  const int quad = L >> 4;       // k-slice / C-row group
  const int u = 16 * w + n;     // hidden unit
  const int hl = n & 1;          // A-row parity: even rows = h_hi, odd = h_lo

  if (t < HBUF) hs[0][t] = (_Float16)0.f;

  // B fragments (persistent, fp16): B[k=quad*8+i][col=n] = w_hh[(g*128+u)*128+k]
  half8 Bw[3][4];
#pragma unroll
  for (int g = 0; g < 3; ++g) {
    const float* row = w_hh + (size_t)(g * 128 + u) * 128;
#pragma unroll
    for (int kt = 0; kt < 4; ++kt) {
      union { _Float16 s[8]; half8 v; } tmp;
#pragma unroll
      for (int i = 0; i < 8; ++i) tmp.s[i] = (_Float16)row[kt * 32 + quad * 8 + i];
      Bw[g][kt] = tmp.v;
    }
  }
  const float bcr  = b_ih[u] + b_hh[u];
  const float bcz  = b_ih[128 + u] + b_hh[128 + u];
  const float bin_ = b_ih[256 + u], bhn = b_hh[256 + u];
  const float wir = w_ih[u], wiz = w_ih[128 + u], win = w_ih[256 + u];

  // per-lane A-read base (halfwords): parity-selected hi/lo bank group
  const int abase = hl * LO_OFF + quad * 8;

  float hprev = 0.f;   // h[u], replicated across quads (identical math)

  // Accumulators persist across steps. Only regs [0],[1] are read
  // (reg0 = even C-row -> hi-dot, reg1 = odd C-row -> lo-dot, since
  // row = 4*quad + reg). Regs [2],[3] carry stale finite garbage across
  // steps (bounded growth, never read) -> init cost is 2 writes/acc/step.
  f32x4 ar = {0.f, 0.f, 0.f, 0.f};
  f32x4 az = {0.f, 0.f, 0.f, 0.f};
  f32x4 an = {0.f, 0.f, 0.f, 0.f};

  __syncthreads();

#define MF(A, B, C) C = __builtin_amdgcn_mfma_f32_16x16x32_f16(A, B, C, 0, 0, 0)

  // One step: read buf RD, write buf WR. A even rows = h_hi, odd rows = h_lo.
  // Input-side preactivation is folded into the accumulator seed (reg0),
  // bhn into the n-gate seed: post-MFMA tail is one add per gate.
#define STEP(RD, WR, XT)                                                       \
  {                                                                            \
    const float xt = (XT);                                                     \
    half8 A[4];                                                                \
    _Pragma("unroll")                                                          \
    for (int kt = 0; kt < 4; ++kt)                                             \
      A[kt] = *(const half8*)&hs[RD][abase + kt * 32];                         \
    ar[0] = fmaf(xt, wir, bcr); ar[1] = 0.f;                                   \
    az[0] = fmaf(xt, wiz, bcz); az[1] = 0.f;                                   \
    an[0] = bhn;                an[1] = 0.f;                                   \
    _Pragma("unroll")                                                          \
    for (int kt = 0; kt < 4; ++kt) {                                           \
      MF(A[kt], Bw[0][kt], ar);                                                \
      MF(A[kt], Bw[1][kt], az);                                                \
      MF(A[kt], Bw[2][kt], an);                                                \
    }                                                                          \
    const float r  = sigmoidf_(ar[0] + ar[1]);                                 \
    const float z  = sigmoidf_(az[0] + az[1]);                                 \
    const float nn = tanhf_(fmaf(r, an[0] + an[1], fmaf(xt, win, bin_)));      \
    hprev = nn + z * (hprev - nn);                                             \
    if (quad == 0) {                                                           \
      const _Float16 hih = (_Float16)hprev;                                    \
      hs[WR][u] = hih;                                                         \
      hs[WR][LO_OFF + u] = (_Float16)(hprev - (float)hih);                     \
    }                                                                          \
    __syncthreads();                                                           \
  }

  // x[b,s] is block-uniform: scalar global loads, prefetched one iteration
  // (~2 steps) ahead; index wrapped &(SEQ-1) to stay in-bounds at the tail.
  const float* xrow = x + (size_t)b * SEQ;
  float x0 = xrow[0], x1 = xrow[1];
  for (int s = 0; s < SEQ; s += 2) {
    const float x2 = xrow[(s + 2) & (SEQ - 1)];
    const float x3 = xrow[(s + 3) & (SEQ - 1)];
    STEP(0, 1, x0);
    STEP(1, 0, x1);
    x0 = x2;
    x1 = x3;
  }
#undef STEP
#undef MF

  // epilogue: out[b] = relu(h_T) . w_fc + b_fc
  float v = (quad == 0) ? fmaxf(hprev, 0.f) * w_fc[u] : 0.f;
#pragma unroll
  for (int off = 1; off < 64; off <<= 1) v += __shfl_xor(v, off);
  if (L == 0) red[w] = v;
  __syncthreads();
  if (t == 0) {
    float sum = 0.f;
#pragma unroll
    for (int k = 0; k < 8; ++k) sum += red[k];
    out[b] = sum + b_fc[0];
  }
}

extern "C" void kernel_launch(void* const* d_in, const int* in_sizes, int n_in,
                              void* d_out, int out_size, void* d_ws, size_t ws_size,
                              hipStream_t stream) {
  const float* x    = (const float*)d_in[0];
  const float* w_ih = (const float*)d_in[1];
  const float* w_hh = (const float*)d_in[2];
  const float* b_ih = (const float*)d_in[3];
  const float* b_hh = (const float*)d_in[4];
  const float* w_fc = (const float*)d_in[5];
  const float* b_fc = (const float*)d_in[6];
  gru_kernel<<<256, NT, 0, stream>>>(x, w_ih, w_hh, b_ih, b_hh, w_fc, b_fc,
                                     (float*)d_out);
}

// Round 4
// 432.602 us; speedup vs baseline: 1.1846x; 1.0787x over previous
//
#include <hip/hip_runtime.h>

#define SEQ 1024
#define NT 512   // 8 waves; wave w owns gate-preact cols [16w,16w+16) for r,z,n

typedef _Float16 half8 __attribute__((ext_vector_type(8)));  // 4 VGPRs
typedef float f32x4 __attribute__((ext_vector_type(4)));     // MFMA 16x16 accum

// h buffer layout (halfwords): [buf][0..127]=h_hi, [buf][160..287]=h_lo.
// lo offset 160 hw = 80 words = bank shift 16 -> a wave's 8 distinct A-read
// addresses (hl in {0,1} x quad in {0..3}) cover all 32 banks exactly once.
#define LO_OFF 160
#define HBUF 320

#define NLOG2E  (-1.4426950408889634f)   // -log2(e): sigmoid via exp2
#define N2LOG2E (-2.8853900817779268f)   // -2*log2(e): tanh via exp2

__global__ __launch_bounds__(NT, 2)
void gru_kernel(const float* __restrict__ x,     // [B, S, 1]
                const float* __restrict__ w_ih,  // [3H, 1]
                const float* __restrict__ w_hh,  // [3H, H]
                const float* __restrict__ b_ih,  // [3H]
                const float* __restrict__ b_hh,  // [3H]
                const float* __restrict__ w_fc,  // [1, H]
                const float* __restrict__ b_fc,  // [1]
                float* __restrict__ out)         // [B, 1]
{
  __shared__ float xs[SEQ + 2];
  __shared__ __align__(16) _Float16 hs[2][HBUF];
  __shared__ float red[8];

  const int t = threadIdx.x;
  const int b = blockIdx.x;
  const int w = t >> 6;          // wave 0..7
  const int L = t & 63;          // lane
  const int n = L & 15;          // MFMA col (unit in tile) == A-row m
  const int quad = L >> 4;       // k-slice / C-row group
  const int u = 16 * w + n;      // hidden unit
  const int hl = n & 1;          // A-row parity: even rows = h_hi, odd = h_lo

  // stage x[b,:] (coalesced); pad 2 zeros for the register prefetch
  const float* xrow = x + (size_t)b * SEQ;
  for (int i = t; i < SEQ + 2; i += NT) xs[i] = (i < SEQ) ? xrow[i] : 0.f;
  if (t < HBUF) hs[0][t] = (_Float16)0.f;

  // B fragments (persistent, fp16), pre-scaled so gate preacts come out of the
  // MFMA already multiplied by -log2e (r,z) / -2log2e (n): exp2 directly.
  half8 Bw[3][4];
#pragma unroll
  for (int g = 0; g < 3; ++g) {
    const float sc = (g == 2) ? N2LOG2E : NLOG2E;
    const float* row = w_hh + (size_t)(g * 128 + u) * 128;
#pragma unroll
    for (int kt = 0; kt < 4; ++kt) {
      union { _Float16 s[8]; half8 v; } tmp;
#pragma unroll
      for (int i = 0; i < 8; ++i)
        tmp.s[i] = (_Float16)(row[kt * 32 + quad * 8 + i] * sc);
      Bw[g][kt] = tmp.v;
    }
  }
  // pre-scaled per-unit scalars (seeds fold input preact + both biases)
  const float bcr = NLOG2E * (b_ih[u] + b_hh[u]);
  const float bcz = NLOG2E * (b_ih[128 + u] + b_hh[128 + u]);
  const float bin_ = N2LOG2E * b_ih[256 + u];
  const float bhn  = N2LOG2E * b_hh[256 + u];
  const float wir = NLOG2E * w_ih[u];
  const float wiz = NLOG2E * w_ih[128 + u];
  const float win = N2LOG2E * w_ih[256 + u];

  // per-lane A-read base (halfwords): parity-selected hi/lo bank group
  const int abase = hl * LO_OFF + quad * 8;

  float hprev = 0.f;   // h[u], replicated across quads (identical math)

  // Persistent accumulators. Only regs [0],[1] are read (reg0 = even C-row ->
  // hi-dot, reg1 = odd C-row -> lo-dot, row = 4*quad + reg). Regs [2],[3]
  // accumulate unread bounded garbage across steps.
  f32x4 ar = {0.f, 0.f, 0.f, 0.f};
  f32x4 az = {0.f, 0.f, 0.f, 0.f};
  f32x4 an = {0.f, 0.f, 0.f, 0.f};

  __syncthreads();

#define MF(A, B, C) C = __builtin_amdgcn_mfma_f32_16x16x32_f16(A, B, C, 0, 0, 0)

  // One step. MFMA order is gate-major-ish: (r,n) pairs then z, so r's dot
  // retires ~4 MFMAs early (its sigmoid overlaps n/z issue) and z retires
  // last (z is only needed at the final h blend).
#define STEP(RD, WR, XT)                                                       \
  {                                                                            \
    const float xt = (XT);                                                     \
    half8 A[4];                                                                \
    _Pragma("unroll")                                                          \
    for (int kt = 0; kt < 4; ++kt)                                             \
      A[kt] = *(const half8*)&hs[RD][abase + kt * 32];                         \
    ar[0] = fmaf(xt, wir, bcr); ar[1] = 0.f;                                   \
    az[0] = fmaf(xt, wiz, bcz); az[1] = 0.f;                                   \
    an[0] = bhn;                an[1] = 0.f;                                   \
    const float in_s = fmaf(xt, win, bin_);                                    \
    MF(A[0], Bw[0][0], ar); MF(A[0], Bw[2][0], an);                            \
    MF(A[1], Bw[0][1], ar); MF(A[1], Bw[2][1], an);                            \
    MF(A[2], Bw[0][2], ar); MF(A[2], Bw[2][2], an);                            \
    MF(A[3], Bw[0][3], ar); MF(A[3], Bw[2][3], an);                            \
    MF(A[0], Bw[1][0], az); MF(A[1], Bw[1][1], az);                            \
    MF(A[2], Bw[1][2], az); MF(A[3], Bw[1][3], az);                            \
    const float r = __builtin_amdgcn_rcpf(                                     \
        1.f + __builtin_amdgcn_exp2f(ar[0] + ar[1]));                          \
    const float e = __builtin_amdgcn_exp2f(fmaf(r, an[0] + an[1], in_s));      \
    const float nn = (1.f - e) * __builtin_amdgcn_rcpf(1.f + e);               \
    const float z = __builtin_amdgcn_rcpf(                                     \
        1.f + __builtin_amdgcn_exp2f(az[0] + az[1]));                          \
    hprev = nn + z * (hprev - nn);                                             \
    const _Float16 hih = (_Float16)hprev;                                      \
    if (quad == 0) hs[WR][u] = hih;                                            \
    if (quad == 1) hs[WR][LO_OFF + u] = (_Float16)(hprev - (float)hih);        \
    __syncthreads();                                                           \
  }

  float x0 = xs[0], x1 = xs[1];
  for (int s = 0; s < SEQ; s += 2) {
    const float xa = xs[s + 2], xb = xs[s + 3];  // LDS prefetch, next iter
    STEP(0, 1, x0);
    STEP(1, 0, x1);
    x0 = xa;
    x1 = xb;
  }
#undef STEP
#undef MF

  // epilogue: out[b] = relu(h_T) . w_fc + b_fc
  float v = (quad == 0) ? fmaxf(hprev, 0.f) * w_fc[u] : 0.f;
#pragma unroll
  for (int off = 1; off < 64; off <<= 1) v += __shfl_xor(v, off);
  if (L == 0) red[w] = v;
  __syncthreads();
  if (t == 0) {
    float sum = 0.f;
#pragma unroll
    for (int k = 0; k < 8; ++k) sum += red[k];
    out[b] = sum + b_fc[0];
  }
}

extern "C" void kernel_launch(void* const* d_in, const int* in_sizes, int n_in,
                              void* d_out, int out_size, void* d_ws, size_t ws_size,
                              hipStream_t stream) {
  const float* x    = (const float*)d_in[0];
  const float* w_ih = (const float*)d_in[1];
  const float* w_hh = (const float*)d_in[2];
  const float* b_ih = (const float*)d_in[3];
  const float* b_hh = (const float*)d_in[4];
  const float* w_fc = (const float*)d_in[5];
  const float* b_fc = (const float*)d_in[6];
  gru_kernel<<<256, NT, 0, stream>>>(x, w_ih, w_hh, b_ih, b_hh, w_fc, b_fc,
                                     (float*)d_out);
}